// Round 8
// baseline (399.597 us; speedup 1.0000x reference)
//
#include <hip/hip_runtime.h>
#include <hip/hip_bf16.h>
#include <math.h>

typedef unsigned int uint;
typedef unsigned short ushort_t;
typedef unsigned char uchar;

typedef __attribute__((ext_vector_type(4))) float f4_t;
typedef __attribute__((ext_vector_type(4))) ushort_t u16x4_t;
typedef __attribute__((ext_vector_type(4))) uint u32x4_t;
typedef __attribute__((ext_vector_type(8))) short bfrag_t;
typedef __attribute__((ext_vector_type(4))) float facc_t;

#define K_DIM 2048
#define D_DIM 256
#define E_DIM 64
#define N_DIM 320
#define S_DIM 4096
#define NTOK 16384
#define KSEL 4096

__device__ __forceinline__ ushort_t f2bf(float f) {
  uint u = __float_as_uint(f);
  uint r = u + 0x7FFFu + ((u >> 16) & 1u);  // RNE
  return (ushort_t)(r >> 16);
}

__device__ __forceinline__ float dot4(f4_t a, f4_t b) {
  return a[0] * b[0] + a[1] * b[1] + a[2] * b[2] + a[3] * b[3];
}

// ---------------- prep: convert weights to bf16, zero accumulators ----------
__global__ __launch_bounds__(256) void prep_kernel(
    const float* __restrict__ W_ts, const float* __restrict__ W_tr,
    ushort_t* __restrict__ Wc, float* __restrict__ zero_region)
{
  int idx = blockIdx.x * 256 + threadIdx.x;       // over N_DIM*K_DIM/4 float4s
  if (idx < (N_DIM * K_DIM / 4)) {
    int n = idx >> 9;                              // / (2048/4)
    int k4 = (idx & 511) * 4;
    const float* src = (n < D_DIM) ? (W_ts + (size_t)n * K_DIM + k4)
                                   : (W_tr + (size_t)(n - D_DIM) * K_DIM + k4);
    f4_t v = *reinterpret_cast<const f4_t*>(src);
    u16x4_t h;
    h[0] = f2bf(v[0]); h[1] = f2bf(v[1]); h[2] = f2bf(v[2]); h[3] = f2bf(v[3]);
    *reinterpret_cast<u16x4_t*>(&Wc[(size_t)n * K_DIM + k4]) = h;
  }
  if (blockIdx.x == 0) {
    for (int i = threadIdx.x; i < 2560; i += 256) zero_region[i] = 0.f;
  }
}

// ---------------- fused GEMM: base_logits + pooled tanh(token_state) --------
// BM=32, 320 thr (5 waves), grid 512 = 2 blocks/CU co-resident (LDS 50.7KB).
// T14 reg-prefetch pipeline (8-deep B). Two desynced blocks per CU hide each
// other's stage/drain phases (R7 grid=256 had 1 block/CU: nothing to overlap).
#define BM 32
#define BK 64
#define LDK 72   // padded row stride in halfs (144 B: 16B-aligned, bank-spread)

__global__ __launch_bounds__(320, 2) void gemm_kernel(
    const float* __restrict__ hidden, const ushort_t* __restrict__ Wc,
    const float* __restrict__ b_ts, const float* __restrict__ b_tr,
    float* __restrict__ base_logits, float* __restrict__ pooled_ts)
{
  __shared__ ushort_t Alds[BM * LDK];      //  4608 B
  __shared__ ushort_t Blds[N_DIM * LDK];   // 46080 B
  const int tid = threadIdx.x;
  const int lane = tid & 63;
  const int wc = tid >> 6;       // 0..4 : N-slice of 64
  const int row0 = blockIdx.x * BM;
  const int lr = lane & 15;
  const int lgp = lane >> 4;
  const bool hasA2 = (tid < 192);          // 512 A-f4-chunks over 320 threads

  const int ar0 = tid >> 4, ac0 = (tid & 15) * 4;
  const int ar1 = (tid + 320) >> 4, ac1 = ((tid + 320) & 15) * 4;

  facc_t acc[2][4];
#pragma unroll
  for (int mi = 0; mi < 2; mi++)
#pragma unroll
    for (int ni = 0; ni < 4; ni++) acc[mi][ni] = (facc_t){0.f, 0.f, 0.f, 0.f};

  f4_t vaA0, vaA1;
  u32x4_t bA0, bA1, bA2, bA3, bA4, bA5, bA6, bA7;
  f4_t vaB0, vaB1;
  u32x4_t bB0, bB1, bB2, bB3, bB4, bB5, bB6, bB7;

#define BLD(k0, kk2) *reinterpret_cast<const u32x4_t*>( \
    Wc + (size_t)((tid + (kk2) * 320) >> 3) * K_DIM + (k0) + ((tid + (kk2) * 320) & 7) * 8)
#define BST(kk2, reg) *reinterpret_cast<u32x4_t*>( \
    &Blds[((tid + (kk2) * 320) >> 3) * LDK + ((tid + (kk2) * 320) & 7) * 8]) = reg

#define LOAD_TILE(k0, vA0, vA1, b0, b1, b2, b3, b4, b5, b6, b7)                  \
  {                                                                              \
    vA0 = *reinterpret_cast<const f4_t*>(hidden + (size_t)(row0 + ar0) * K_DIM + (k0) + ac0); \
    if (hasA2)                                                                   \
      vA1 = *reinterpret_cast<const f4_t*>(hidden + (size_t)(row0 + ar1) * K_DIM + (k0) + ac1); \
    b0 = BLD(k0, 0); b1 = BLD(k0, 1); b2 = BLD(k0, 2); b3 = BLD(k0, 3);          \
    b4 = BLD(k0, 4); b5 = BLD(k0, 5); b6 = BLD(k0, 6); b7 = BLD(k0, 7);          \
  }

#define STORE_TILE(vA0, vA1, b0, b1, b2, b3, b4, b5, b6, b7)                     \
  {                                                                              \
    u16x4_t h;                                                                   \
    h[0] = f2bf(vA0[0]); h[1] = f2bf(vA0[1]); h[2] = f2bf(vA0[2]); h[3] = f2bf(vA0[3]); \
    *reinterpret_cast<u16x4_t*>(&Alds[ar0 * LDK + ac0]) = h;                     \
    if (hasA2) {                                                                 \
      h[0] = f2bf(vA1[0]); h[1] = f2bf(vA1[1]); h[2] = f2bf(vA1[2]); h[3] = f2bf(vA1[3]); \
      *reinterpret_cast<u16x4_t*>(&Alds[ar1 * LDK + ac1]) = h;                   \
    }                                                                            \
    BST(0, b0); BST(1, b1); BST(2, b2); BST(3, b3);                              \
    BST(4, b4); BST(5, b5); BST(6, b6); BST(7, b7);                              \
  }

#define COMPUTE_TILE()                                                           \
  {                                                                              \
    _Pragma("unroll")                                                            \
    for (int kk = 0; kk < 2; ++kk) {                                             \
      bfrag_t af[2], bfv[4];                                                     \
      _Pragma("unroll")                                                          \
      for (int mi = 0; mi < 2; mi++)                                             \
        af[mi] = *reinterpret_cast<const bfrag_t*>(&Alds[(mi * 16 + lr) * LDK + kk * 32 + lgp * 8]); \
      _Pragma("unroll")                                                          \
      for (int ni = 0; ni < 4; ni++)                                             \
        bfv[ni] = *reinterpret_cast<const bfrag_t*>(&Blds[(wc * 64 + ni * 16 + lr) * LDK + kk * 32 + lgp * 8]); \
      _Pragma("unroll")                                                          \
      for (int mi = 0; mi < 2; mi++)                                             \
        _Pragma("unroll")                                                        \
        for (int ni = 0; ni < 4; ni++)                                           \
          acc[mi][ni] = __builtin_amdgcn_mfma_f32_16x16x32_bf16(af[mi], bfv[ni], acc[mi][ni], 0, 0, 0); \
    }                                                                            \
  }

  LOAD_TILE(0, vaA0, vaA1, bA0, bA1, bA2, bA3, bA4, bA5, bA6, bA7);

#pragma unroll 1
  for (int t = 0; t < 32; t += 2) {
    __syncthreads();
    STORE_TILE(vaA0, vaA1, bA0, bA1, bA2, bA3, bA4, bA5, bA6, bA7);
    LOAD_TILE((t + 1) * BK, vaB0, vaB1, bB0, bB1, bB2, bB3, bB4, bB5, bB6, bB7);
    __syncthreads();
    COMPUTE_TILE();

    __syncthreads();
    STORE_TILE(vaB0, vaB1, bB0, bB1, bB2, bB3, bB4, bB5, bB6, bB7);
    if (t + 2 < 32)
      LOAD_TILE((t + 2) * BK, vaA0, vaA1, bA0, bA1, bA2, bA3, bA4, bA5, bA6, bA7);
    __syncthreads();
    COMPUTE_TILE();
  }

  const int b = row0 >> 12;  // batch (4096 rows per batch, 32 | 4096)
  if (wc < 4) {
#pragma unroll
    for (int ni = 0; ni < 4; ni++) {
      const int col = wc * 64 + ni * 16 + lr;
      const float bias = b_ts[col];
      float psum = 0.f;
#pragma unroll
      for (int mi = 0; mi < 2; mi++)
#pragma unroll
        for (int j = 0; j < 4; j++)
          psum += tanhf(acc[mi][ni][j] + bias);
      psum += __shfl_xor(psum, 16, 64);
      psum += __shfl_xor(psum, 32, 64);
      if (lgp == 0) atomicAdd(&pooled_ts[b * D_DIM + col], psum);
    }
  } else {
#pragma unroll
    for (int ni = 0; ni < 4; ni++) {
      const int e = ni * 16 + lr;
      const float bias = b_tr[e];
#pragma unroll
      for (int mi = 0; mi < 2; mi++)
#pragma unroll
        for (int j = 0; j < 4; j++) {
          const int row = row0 + mi * 16 + lgp * 4 + j;
          base_logits[(size_t)row * E_DIM + e] = acc[mi][ni][j] + bias;
        }
    }
  }
}

// ---------------- per-round softmax / margins / pooling ---------------------
__global__ __launch_bounds__(256) void route_kernel(
    int round,
    const float* __restrict__ base_logits,
    const float* __restrict__ bias1, const float* __restrict__ bias2,
    const uchar* __restrict__ active, uchar* __restrict__ tag,
    float* __restrict__ margins, float* __restrict__ pw_out,
    float* __restrict__ out)
{
  __shared__ float sm[4][64];
  const int tid = threadIdx.x;
  const int lane = tid & 63;
  const int wid = tid >> 6;
  const int b = blockIdx.x >> 8;   // 16 tokens/block, 256 blocks/batch
  const int t0 = blockIdx.x * 16 + wid * 4;

  float bv1 = 0.f, bv2 = 0.f;
  if (round >= 1) bv1 = bias1[b * E_DIM + lane];
  if (round == 2) bv2 = bias2[b * E_DIM + lane];

  float lg[4];
#pragma unroll
  for (int i = 0; i < 4; ++i)
    lg[i] = base_logits[(size_t)(t0 + i) * E_DIM + lane];

  if (round == 1) {
    uchar a[4];
#pragma unroll
    for (int i = 0; i < 4; ++i) a[i] = active[t0 + i];
#pragma unroll
    for (int i = 0; i < 4; ++i) {
      if (lane == 0) tag[t0 + i] = a[i];
      if (a[i]) lg[i] += bv1;
    }
  } else if (round == 2) {
    uchar a[4], tg[4];
#pragma unroll
    for (int i = 0; i < 4; ++i) { a[i] = active[t0 + i]; tg[i] = tag[t0 + i]; }
#pragma unroll
    for (int i = 0; i < 4; ++i)
      lg[i] += a[i] ? bv2 : (tg[i] ? bv1 : 0.f);
  }

  float pacc = 0.f;
#pragma unroll
  for (int i = 0; i < 4; ++i) {
    const float lgt = lg[i];
    float m1 = lgt;
#pragma unroll
    for (int mm = 32; mm; mm >>= 1) m1 = fmaxf(m1, __shfl_xor(m1, mm, 64));
    float e = expf(lgt - m1);
    float s = e;
#pragma unroll
    for (int mm = 32; mm; mm >>= 1) s += __shfl_xor(s, mm, 64);
    if (round == 2) {
      out[(size_t)(t0 + i) * E_DIM + lane] = e / s;
    } else {
      pacc += e / s;
      unsigned long long bal = __ballot(lgt == m1);
      int first = __ffsll((unsigned long long)bal) - 1;
      float l2 = (lane == first) ? -__builtin_inff() : lgt;
#pragma unroll
      for (int mm = 32; mm; mm >>= 1) l2 = fmaxf(l2, __shfl_xor(l2, mm, 64));
      if (lane == 0) margins[t0 + i] = (1.f - expf(l2 - m1)) / s;  // top1-top2 of weights
    }
  }
  if (round != 2) {
    sm[wid][lane] = pacc;
    __syncthreads();
    if (wid == 0) {
      float v = sm[0][lane] + sm[1][lane] + sm[2][lane] + sm[3][lane];
      atomicAdd(&pw_out[b * E_DIM + lane], v);
    }
  }
}

// ---------------- mid stage kernels ------------------------------------------
// R7 post-mortem: fused mid ran on 5 CUs; each GRU block read ~1.1MB cold
// weights at per-CU HBM rate (~25GB/s) => ~70us. Split into stage kernels;
// each block owns a ROW-RANGE for ALL 4 batches so weights are read exactly
// once chip-wide, spread across CUs. Grid-sync via kernel boundaries.

// midA: blocks 0-3: stage0 si = (pooled_ts + W_fb@pw)/4096 ; block 4: select
__global__ __launch_bounds__(1024) void midA_kernel(
    const float* __restrict__ margins, const float* __restrict__ pw,
    const float* __restrict__ W_fb, const float* __restrict__ pooled_ts,
    float* __restrict__ si_buf, uchar* __restrict__ active)
{
  const int tid = threadIdx.x;
  const int lane = tid & 63;
  const int wid = tid >> 6;
  if (blockIdx.x < 4) {
    __shared__ __align__(16) float pwl[256];
    if (tid < 256) pwl[tid] = pw[tid];
    __syncthreads();
    if (tid < 256) {
      const int r = blockIdx.x * 64 + (tid >> 2), q = tid & 3;
      const float* wr = W_fb + r * 64 + q * 16;
      f4_t w0 = *reinterpret_cast<const f4_t*>(wr);
      f4_t w1 = *reinterpret_cast<const f4_t*>(wr + 4);
      f4_t w2 = *reinterpret_cast<const f4_t*>(wr + 8);
      f4_t w3 = *reinterpret_cast<const f4_t*>(wr + 12);
      float sb[4];
#pragma unroll
      for (int b2 = 0; b2 < 4; ++b2) {
        const float* xb = &pwl[b2 * 64 + q * 16];
        sb[b2] = dot4(w0, *reinterpret_cast<const f4_t*>(xb))
               + dot4(w1, *reinterpret_cast<const f4_t*>(xb + 4))
               + dot4(w2, *reinterpret_cast<const f4_t*>(xb + 8))
               + dot4(w3, *reinterpret_cast<const f4_t*>(xb + 12));
      }
#pragma unroll
      for (int b2 = 0; b2 < 4; ++b2) {
        sb[b2] += __shfl_xor(sb[b2], 1, 64);
        sb[b2] += __shfl_xor(sb[b2], 2, 64);
      }
      if (q == 0) {
#pragma unroll
        for (int b2 = 0; b2 < 4; ++b2)
          si_buf[b2 * 256 + r] = (pooled_ts[b2 * 256 + r] + sb[b2]) * (1.f / 4096.f);
      }
    }
  } else {
    // exact k-smallest radix select; all 4 passes run from registers
    __shared__ uint hist[256];
    __shared__ uint aux2[4];     // [0]=pick [1]=kknew [2]=c_lt [3]=need
    __shared__ uint wsum[16];
    const u32x4_t* mv = reinterpret_cast<const u32x4_t*>(margins);
    u32x4_t loc[4];
#pragma unroll
    for (int q = 0; q < 4; ++q) loc[q] = mv[tid * 4 + q];
    uint pfx = 0, kk = KSEL;
    for (int shift = 24; shift >= 0; shift -= 8) {
      if (tid < 256) hist[tid] = 0;
      __syncthreads();
#pragma unroll
      for (int q = 0; q < 4; ++q) {
#pragma unroll
        for (int e = 0; e < 4; ++e) {
          uint u = loc[q][e];
          bool ok = (shift == 24) || ((u >> (shift + 8)) == (pfx >> (shift + 8)));
          uint bin = (u >> shift) & 255u;
          unsigned long long m = __ballot(ok);
#pragma unroll
          for (int bit = 0; bit < 8; ++bit) {
            unsigned long long bb = __ballot(ok && ((bin >> bit) & 1u));
            m &= ((bin >> bit) & 1u) ? bb : ~bb;
          }
          if (ok && (__ffsll(m) - 1) == lane) atomicAdd(&hist[bin], (uint)__popcll(m));
        }
      }
      __syncthreads();
      uint hv = 0, hx = 0;
      if (tid < 256) {
        hv = hist[tid];
        hx = hv;
#pragma unroll
        for (int d = 1; d < 64; d <<= 1) {
          uint y = __shfl_up(hx, d, 64);
          if (lane >= d) hx += y;
        }
        if (lane == 63) wsum[wid] = hx;
      }
      __syncthreads();
      if (tid < 256) {
        uint base = 0;
        for (int w2 = 0; w2 < 4; ++w2) base += (w2 < wid) ? wsum[w2] : 0u;
        uint inc = hx + base;
        if (inc >= kk && (inc - hv) < kk) { aux2[0] = (uint)tid; aux2[1] = kk - (inc - hv); }
      }
      __syncthreads();
      pfx |= aux2[0] << shift;
      kk = aux2[1];
      __syncthreads();
    }
    const uint tval = pfx;
    if (tid == 0) aux2[2] = 0;
    __syncthreads();
    uint myLt = 0, myEq = 0;
#pragma unroll
    for (int q = 0; q < 4; ++q) {
#pragma unroll
      for (int e = 0; e < 4; ++e) {
        uint u = loc[q][e];
        myLt += (u < tval) ? 1u : 0u;
        myEq += (u == tval) ? 1u : 0u;
      }
    }
    uint lt = myLt;
#pragma unroll
    for (int m = 32; m; m >>= 1) lt += __shfl_xor(lt, m, 64);
    if (lane == 0) atomicAdd(&aux2[2], lt);
    uint x = myEq;
#pragma unroll
    for (int d = 1; d < 64; d <<= 1) {
      uint y = __shfl_up(x, d, 64);
      if (lane >= d) x += y;
    }
    if (lane == 63) wsum[wid] = x;
    __syncthreads();
    if (tid == 0) {
      uint run = 0;
      for (int w2 = 0; w2 < 16; ++w2) { uint c = wsum[w2]; wsum[w2] = run; run += c; }
      aux2[3] = (uint)KSEL - aux2[2];
    }
    __syncthreads();
    uint pos = wsum[wid] + (x - myEq);
    const uint need = aux2[3];
#pragma unroll
    for (int q = 0; q < 4; ++q) {
#pragma unroll
      for (int e = 0; e < 4; ++e) {
        uint u = loc[q][e];
        uchar a = 0;
        if (u < tval) a = 1;
        else if (u == tval) { a = (pos < need) ? 1 : 0; pos++; }
        active[tid * 16 + q * 4 + e] = a;
      }
    }
  }
}

// gru2: 12 blocks: mat m = blk>>2 in {W_r,W_z,W_ci}, rows [(blk&3)*64,+64)
__global__ __launch_bounds__(256) void gru2_kernel(
    const float* __restrict__ W_r, const float* __restrict__ W_z,
    const float* __restrict__ W_ci, const float* __restrict__ b_r,
    const float* __restrict__ b_z, const float* __restrict__ b_ci,
    const float* __restrict__ si_buf, const float* __restrict__ ctrl,
    float* __restrict__ rcs_buf, float* __restrict__ zgs_buf,
    float* __restrict__ ais_buf)
{
  __shared__ __align__(16) float sil[1024];
  const int tid = threadIdx.x;
  for (int i = tid; i < 1024; i += 256) sil[i] = si_buf[i];
  __syncthreads();
  const int m = blockIdx.x >> 2;
  const int r = (blockIdx.x & 3) * 64 + (tid >> 2), q = tid & 3;
  const float* wr = ((m == 0) ? W_r : (m == 1) ? W_z : W_ci) + r * 256 + q * 64;
  float s0 = 0.f, s1 = 0.f, s2 = 0.f, s3 = 0.f;
#pragma unroll
  for (int j = 0; j < 16; ++j) {
    f4_t wv = *reinterpret_cast<const f4_t*>(wr + j * 4);
    s0 += dot4(wv, *reinterpret_cast<const f4_t*>(&sil[q * 64 + j * 4]));
    s1 += dot4(wv, *reinterpret_cast<const f4_t*>(&sil[256 + q * 64 + j * 4]));
    s2 += dot4(wv, *reinterpret_cast<const f4_t*>(&sil[512 + q * 64 + j * 4]));
    s3 += dot4(wv, *reinterpret_cast<const f4_t*>(&sil[768 + q * 64 + j * 4]));
  }
  s0 += __shfl_xor(s0, 1, 64); s0 += __shfl_xor(s0, 2, 64);
  s1 += __shfl_xor(s1, 1, 64); s1 += __shfl_xor(s1, 2, 64);
  s2 += __shfl_xor(s2, 1, 64); s2 += __shfl_xor(s2, 2, 64);
  s3 += __shfl_xor(s3, 1, 64); s3 += __shfl_xor(s3, 2, 64);
  if (q == 0) {
    float sv[4] = {s0, s1, s2, s3};
    if (m == 0) {
      const float bb = b_r[r];
#pragma unroll
      for (int b2 = 0; b2 < 4; ++b2)
        rcs_buf[b2 * 256 + r] = ctrl[b2 * 256 + r] / (1.f + expf(-(sv[b2] + bb)));
    } else if (m == 1) {
      const float bb = b_z[r];
#pragma unroll
      for (int b2 = 0; b2 < 4; ++b2)
        zgs_buf[b2 * 256 + r] = 1.f / (1.f + expf(-(sv[b2] + bb)));
    } else {
      const float bb = b_ci[r];
#pragma unroll
      for (int b2 = 0; b2 < 4; ++b2)
        ais_buf[b2 * 256 + r] = sv[b2] + bb;
    }
  }
}

// gru3: 4 blocks: W_cs rows [blk*64,+64); GRU combine, updates ctrl
__global__ __launch_bounds__(256) void gru3_kernel(
    const float* __restrict__ W_cs, const float* __restrict__ rcs_buf,
    const float* __restrict__ zgs_buf, const float* __restrict__ ais_buf,
    float* __restrict__ ctrl, float* __restrict__ cns_buf)
{
  __shared__ __align__(16) float rl[1024];
  const int tid = threadIdx.x;
  for (int i = tid; i < 1024; i += 256) rl[i] = rcs_buf[i];
  __syncthreads();
  const int r = blockIdx.x * 64 + (tid >> 2), q = tid & 3;
  const float* wr = W_cs + r * 256 + q * 64;
  float s0 = 0.f, s1 = 0.f, s2 = 0.f, s3 = 0.f;
#pragma unroll
  for (int j = 0; j < 16; ++j) {
    f4_t wv = *reinterpret_cast<const f4_t*>(wr + j * 4);
    s0 += dot4(wv, *reinterpret_cast<const f4_t*>(&rl[q * 64 + j * 4]));
    s1 += dot4(wv, *reinterpret_cast<const f4_t*>(&rl[256 + q * 64 + j * 4]));
    s2 += dot4(wv, *reinterpret_cast<const f4_t*>(&rl[512 + q * 64 + j * 4]));
    s3 += dot4(wv, *reinterpret_cast<const f4_t*>(&rl[768 + q * 64 + j * 4]));
  }
  s0 += __shfl_xor(s0, 1, 64); s0 += __shfl_xor(s0, 2, 64);
  s1 += __shfl_xor(s1, 1, 64); s1 += __shfl_xor(s1, 2, 64);
  s2 += __shfl_xor(s2, 1, 64); s2 += __shfl_xor(s2, 2, 64);
  s3 += __shfl_xor(s3, 1, 64); s3 += __shfl_xor(s3, 2, 64);
  if (q == 0) {
    float sv[4] = {s0, s1, s2, s3};
#pragma unroll
    for (int b2 = 0; b2 < 4; ++b2) {
      float cold = ctrl[b2 * 256 + r];
      float zg = zgs_buf[b2 * 256 + r];
      float cnew = (1.f - zg) * cold + zg * tanhf(ais_buf[b2 * 256 + r] + sv[b2]);
      ctrl[b2 * 256 + r] = cnew;
      cns_buf[b2 * 256 + r] = cnew;
    }
  }
}

// gru4: 1 block: bias_out = W_sr @ ctrl (64 rows x 4 batches)
__global__ __launch_bounds__(256) void gru4_kernel(
    const float* __restrict__ W_sr, const float* __restrict__ cns_buf,
    float* __restrict__ bias_out)
{
  __shared__ __align__(16) float cl[1024];
  const int tid = threadIdx.x;
  for (int i = tid; i < 1024; i += 256) cl[i] = cns_buf[i];
  __syncthreads();
  const int r = tid >> 2, q = tid & 3;
  const float* wr = W_sr + r * 256 + q * 64;
  float s0 = 0.f, s1 = 0.f, s2 = 0.f, s3 = 0.f;
#pragma unroll
  for (int j = 0; j < 16; ++j) {
    f4_t wv = *reinterpret_cast<const f4_t*>(wr + j * 4);
    s0 += dot4(wv, *reinterpret_cast<const f4_t*>(&cl[q * 64 + j * 4]));
    s1 += dot4(wv, *reinterpret_cast<const f4_t*>(&cl[256 + q * 64 + j * 4]));
    s2 += dot4(wv, *reinterpret_cast<const f4_t*>(&cl[512 + q * 64 + j * 4]));
    s3 += dot4(wv, *reinterpret_cast<const f4_t*>(&cl[768 + q * 64 + j * 4]));
  }
  s0 += __shfl_xor(s0, 1, 64); s0 += __shfl_xor(s0, 2, 64);
  s1 += __shfl_xor(s1, 1, 64); s1 += __shfl_xor(s1, 2, 64);
  s2 += __shfl_xor(s2, 1, 64); s2 += __shfl_xor(s2, 2, 64);
  s3 += __shfl_xor(s3, 1, 64); s3 += __shfl_xor(s3, 2, 64);
  if (q == 0) {
    bias_out[r]       = s0;
    bias_out[64 + r]  = s1;
    bias_out[128 + r] = s2;
    bias_out[192 + r] = s3;
  }
}

// ---------------- launch ----------------------------------------------------
extern "C" void kernel_launch(void* const* d_in, const int* in_sizes, int n_in,
                              void* d_out, int out_size, void* d_ws, size_t ws_size,
                              hipStream_t stream) {
  const float* hidden = (const float*)d_in[0];
  const float* W_ts = (const float*)d_in[1];
  const float* b_ts = (const float*)d_in[2];
  const float* W_tr = (const float*)d_in[3];
  const float* b_tr = (const float*)d_in[4];
  const float* W_sr = (const float*)d_in[5];
  const float* W_fb = (const float*)d_in[6];
  const float* W_r  = (const float*)d_in[7];
  const float* b_r  = (const float*)d_in[8];
  const float* W_z  = (const float*)d_in[9];
  const float* b_z  = (const float*)d_in[10];
  const float* W_ci = (const float*)d_in[11];
  const float* b_ci = (const float*)d_in[12];
  const float* W_cs = (const float*)d_in[13];
  float* out = (float*)d_out;

  char* ws = (char*)d_ws;
  float* base_logits = (float*)(ws);                                   // 4 MB
  ushort_t* Wc = (ushort_t*)(ws + (4u << 20));                         // 1.25 MB
  float* margins = (float*)(ws + (4u << 20) + 1310720u);               // 64 KB
  uchar* active = (uchar*)(ws + (4u << 20) + 1310720u + 65536u);       // 16 KB
  uchar* tag    = (uchar*)(ws + (4u << 20) + 1310720u + 65536u + 16384u); // 16 KB
  float* pooled_ts = (float*)(ws + (4u << 20) + 1310720u + 65536u + 32768u);
  float* pw0   = pooled_ts + 1024;
  float* pw1   = pw0 + 256;
  float* ctrl  = pw1 + 256;     // end of contiguous zero_region (2560 floats)
  float* bias1 = ctrl + 1024;
  float* bias2 = bias1 + 256;
  float* si_buf  = bias2 + 256;
  float* rcs_buf = si_buf + 1024;
  float* zgs_buf = rcs_buf + 1024;
  float* ais_buf = zgs_buf + 1024;
  float* cns_buf = ais_buf + 1024;

  prep_kernel<<<640, 256, 0, stream>>>(W_ts, W_tr, Wc, pooled_ts);
  gemm_kernel<<<512, 320, 0, stream>>>(hidden, Wc, b_ts, b_tr, base_logits, pooled_ts);
  route_kernel<<<1024, 256, 0, stream>>>(0, base_logits, nullptr, nullptr, nullptr, nullptr,
                                         margins, pw0, nullptr);
  midA_kernel<<<5, 1024, 0, stream>>>(margins, pw0, W_fb, pooled_ts, si_buf, active);
  gru2_kernel<<<12, 256, 0, stream>>>(W_r, W_z, W_ci, b_r, b_z, b_ci, si_buf, ctrl,
                                      rcs_buf, zgs_buf, ais_buf);
  gru3_kernel<<<4, 256, 0, stream>>>(W_cs, rcs_buf, zgs_buf, ais_buf, ctrl, cns_buf);
  gru4_kernel<<<1, 256, 0, stream>>>(W_sr, cns_buf, bias1);
  route_kernel<<<1024, 256, 0, stream>>>(1, base_logits, bias1, nullptr, active, tag,
                                         margins, pw1, nullptr);
  midA_kernel<<<5, 1024, 0, stream>>>(margins, pw1, W_fb, pooled_ts, si_buf, active);
  gru2_kernel<<<12, 256, 0, stream>>>(W_r, W_z, W_ci, b_r, b_z, b_ci, si_buf, ctrl,
                                      rcs_buf, zgs_buf, ais_buf);
  gru3_kernel<<<4, 256, 0, stream>>>(W_cs, rcs_buf, zgs_buf, ais_buf, ctrl, cns_buf);
  gru4_kernel<<<1, 256, 0, stream>>>(W_sr, cns_buf, bias2);
  route_kernel<<<1024, 256, 0, stream>>>(2, base_logits, bias1, bias2, active, tag,
                                         nullptr, nullptr, out);
}